// Round 2
// baseline (26450.491 us; speedup 1.0000x reference)
//
#include <hip/hip_runtime.h>

// Output layout (flat f32, reference return order):
//   xhat  : B*L*N   = 13,107,200  @ 0
//   mu    : B*D     =      4,096  @ 13,107,200
//   logvar: B*D     =      4,096  @ 13,111,296
//   z_traj: B*L*D   =    819,200  @ 13,115,392
//   zdiff : B*(L-1)*D =  815,104  @ 13,934,592
#define OFF_MU   13107200
#define OFF_LV   13111296
#define OFF_ZT   13115392
#define OFF_ZD   13934592

__device__ __forceinline__ float silu_f(float x) {
    return x * __frcp_rn(1.0f + __expf(-x));
}

// DPP row-rotate add: x + rotate_within_row16(x, N). Rotation-based butterfly:
// s+=ror8(s); s+=ror4(s); s+=ror2(s); s+=ror1(s)  => every lane = row sum.
template <int CTRL>
__device__ __forceinline__ float dpp_ror_add(float x) {
    int y = __builtin_amdgcn_update_dpp(0, __float_as_int(x), CTRL, 0xF, 0xF, true);
    return x + __int_as_float(y);
}
__device__ __forceinline__ float row_sum16(float x) {
    x = dpp_ror_add<0x128>(x);   // row_ror:8
    x = dpp_ror_add<0x124>(x);   // row_ror:4
    x = dpp_ror_add<0x122>(x);   // row_ror:2
    x = dpp_ror_add<0x121>(x);   // row_ror:1
    return x;
}

// ---------------------------------------------------------------------------
// Encoder: one block per batch row. x0(256) -> 512 -> 256 -> 128 -> mu/lv(16)
// ---------------------------------------------------------------------------
__global__ __launch_bounds__(256) void enc_kernel(
    const float* __restrict__ xseq, const float* __restrict__ eps,
    const float* __restrict__ w1, const float* __restrict__ b1,
    const float* __restrict__ w2, const float* __restrict__ b2,
    const float* __restrict__ w3, const float* __restrict__ b3,
    const float* __restrict__ muw, const float* __restrict__ mub,
    const float* __restrict__ lvw, const float* __restrict__ lvb,
    float* __restrict__ out)
{
    __shared__ float xr[256];
    __shared__ float h1[512];
    __shared__ float h2[256];
    __shared__ float h3[128];

    const int t = threadIdx.x;
    const int b = blockIdx.x;

    xr[t] = xseq[b * (200 * 256) + t];
    __syncthreads();

    {
        float acc0 = b1[t], acc1 = b1[t + 256];
        for (int i = 0; i < 256; ++i) {
            float xv = xr[i];
            acc0 = fmaf(xv, w1[i * 512 + t],       acc0);
            acc1 = fmaf(xv, w1[i * 512 + t + 256], acc1);
        }
        h1[t]       = fmaxf(acc0, 0.0f);
        h1[t + 256] = fmaxf(acc1, 0.0f);
    }
    __syncthreads();

    {
        float acc = b2[t];
        for (int i = 0; i < 512; ++i) acc = fmaf(h1[i], w2[i * 256 + t], acc);
        h2[t] = fmaxf(acc, 0.0f);
    }
    __syncthreads();

    if (t < 128) {
        float acc = b3[t];
        for (int i = 0; i < 256; ++i) acc = fmaf(h2[i], w3[i * 128 + t], acc);
        h3[t] = fmaxf(acc, 0.0f);
    }
    __syncthreads();

    if (t < 16) {
        float mu = mub[t], lv = lvb[t];
        for (int i = 0; i < 128; ++i) {
            float hv = h3[i];
            mu = fmaf(hv, muw[i * 16 + t], mu);
            lv = fmaf(hv, lvw[i * 16 + t], lv);
        }
        out[OFF_MU + b * 16 + t] = mu;
        out[OFF_LV + b * 16 + t] = lv;
        float z0 = mu + __expf(0.5f * lv) * eps[b * 16 + t];
        out[OFF_ZT + b * 3200 + t] = z0;
    }
}

// ---------------------------------------------------------------------------
// ODE integrator: ONE 64-lane WAVE per batch element (256 blocks x 64 thr).
// Single-wave workgroup => __syncthreads lowers to s_waitcnt lgkmcnt(0) only
// (no s_barrier). Lane = (row r = tid>>4, dim d = tid&15); z and k1..k5 are
// per-lane scalars replicated across the 4 rows (identical arithmetic keeps
// rows coherent). w2 columns live in registers (2 cols x 128 K = 256 VGPRs).
// LN reduction over D=16 via DPP row_ror (no LDS, no bpermute).
// ---------------------------------------------------------------------------
__global__ __launch_bounds__(64, 1) void ode_kernel(
    const float* __restrict__ tvec,
    const float* __restrict__ ow1, const float* __restrict__ ob1,
    const float* __restrict__ ow2, const float* __restrict__ ob2,
    const float* __restrict__ ow3, const float* __restrict__ ob3,
    const float* __restrict__ lng, const float* __restrict__ lnb,
    float* __restrict__ out)
{
    __shared__ __align__(16) float zargS[16];
    __shared__ __align__(16) float a1s[128];
    __shared__ __align__(16) float a2s[128];
    __shared__ __align__(16) float p3s[64];   // [d][r] at index d*4+r

    const int lane = threadIdx.x;
    const int b    = blockIdx.x;
    const int r    = lane >> 4;
    const int d    = lane & 15;
    const int j0   = lane;
    const int j1   = lane + 64;

    // ---- register-resident weights ----
    float w1r0[16], w1r1[16];
#pragma unroll
    for (int k = 0; k < 16; ++k) {
        w1r0[k] = ow1[k * 128 + j0];
        w1r1[k] = ow1[k * 128 + j1];
    }
    float w2r0[128], w2r1[128];
#pragma unroll
    for (int k = 0; k < 128; ++k) {
        w2r0[k] = ow2[k * 128 + j0];
        w2r1[k] = ow2[k * 128 + j1];
    }
    float w3r[32];
#pragma unroll
    for (int i = 0; i < 32; ++i) w3r[i] = ow3[(32 * r + i) * 16 + d];

    const float b1j0 = ob1[j0], b1j1 = ob1[j1];
    const float b2j0 = ob2[j0], b2j1 = ob2[j1];
    const float b3d  = ob3[d];
    const float lngd = lng[d];
    const float lnbd = lnb[d];

    float* ztraj = out + OFF_ZT + b * 3200;   // [200][16]
    float* zdiff = out + OFF_ZD + b * 3184;   // [199][16]

    float z = ztraj[d];   // broadcast read; replicated across rows

    // one f-eval: input = per-lane zarg scalar (dim d), output = LN(dz)[d]
    auto feval = [&](float za) -> float {
        if (lane < 16) zargS[lane] = za;      // row 0 publishes zarg
        __syncthreads();
        float zk[16];
        {
            const float4* Z4 = (const float4*)zargS;
            float4 z0v = Z4[0], z1v = Z4[1], z2v = Z4[2], z3v = Z4[3];
            zk[0]=z0v.x; zk[1]=z0v.y; zk[2]=z0v.z; zk[3]=z0v.w;
            zk[4]=z1v.x; zk[5]=z1v.y; zk[6]=z1v.z; zk[7]=z1v.w;
            zk[8]=z2v.x; zk[9]=z2v.y; zk[10]=z2v.z; zk[11]=z2v.w;
            zk[12]=z3v.x; zk[13]=z3v.y; zk[14]=z3v.z; zk[15]=z3v.w;
        }
        // L1: 2 columns, K=16
        float acc0 = b1j0, acc1 = b1j1;
#pragma unroll
        for (int k = 0; k < 16; ++k) {
            acc0 = fmaf(zk[k], w1r0[k], acc0);
            acc1 = fmaf(zk[k], w1r1[k], acc1);
        }
        a1s[j0] = silu_f(acc0);
        a1s[j1] = silu_f(acc1);
        __syncthreads();

        // L2: 2 columns, K=128, a1 via broadcast float4 reads
        float c0 = b2j0, c1 = b2j1;
        const float4* A4 = (const float4*)a1s;
#pragma unroll
        for (int p = 0; p < 32; ++p) {
            float4 a = A4[p];
            c0 = fmaf(a.x, w2r0[4*p+0], c0);
            c0 = fmaf(a.y, w2r0[4*p+1], c0);
            c0 = fmaf(a.z, w2r0[4*p+2], c0);
            c0 = fmaf(a.w, w2r0[4*p+3], c0);
            c1 = fmaf(a.x, w2r1[4*p+0], c1);
            c1 = fmaf(a.y, w2r1[4*p+1], c1);
            c1 = fmaf(a.z, w2r1[4*p+2], c1);
            c1 = fmaf(a.w, w2r1[4*p+3], c1);
        }
        a2s[j0] = silu_f(c0);
        a2s[j1] = silu_f(c1);
        __syncthreads();

        // L3 partial: lane (r,d) covers k in [32r, 32r+32); staggered reads so
        // the 4 rows hit disjoint bank groups each step.
        float part = 0.0f;
        const float4* B4 = (const float4*)a2s;
#pragma unroll
        for (int t = 0; t < 8; ++t) {
            int i = (t + 2 * r) & 7;
            float4 a = B4[r * 8 + i];
            part = fmaf(a.x, w3r[4*i+0], part);
            part = fmaf(a.y, w3r[4*i+1], part);
            part = fmaf(a.z, w3r[4*i+2], part);
            part = fmaf(a.w, w3r[4*i+3], part);
        }
        p3s[d * 4 + r] = part;
        __syncthreads();
        float4 pv = ((const float4*)p3s)[d];
        float dz = pv.x + pv.y + pv.z + pv.w + b3d;

        // LayerNorm over the 16 dims (intra-row DPP reduction)
        float m  = row_sum16(dz) * 0.0625f;
        float df = dz - m;
        float v  = row_sum16(df * df) * 0.0625f;
        return df * rsqrtf(v + 1e-5f) * lngd + lnbd;
    };

    for (int iv = 0; iv < 199; ++iv) {
        const float dt = tvec[iv + 1] - tvec[iv];
        const float h  = dt * 0.125f;
        const float zstart = z;
        for (int s = 0; s < 8; ++s) {
            float k1 = feval(z);
            float k2 = feval(z + h * (0.2f * k1));
            float k3 = feval(z + h * ((float)(3.0/40.0)*k1 + (float)(9.0/40.0)*k2));
            float k4 = feval(z + h * ((float)(44.0/45.0)*k1 - (float)(56.0/15.0)*k2
                                    + (float)(32.0/9.0)*k3));
            float k5 = feval(z + h * ((float)(19372.0/6561.0)*k1 - (float)(25360.0/2187.0)*k2
                                    + (float)(64448.0/6561.0)*k3 - (float)(212.0/729.0)*k4));
            float k6 = feval(z + h * ((float)(9017.0/3168.0)*k1 - (float)(355.0/33.0)*k2
                                    + (float)(46732.0/5247.0)*k3 + (float)(49.0/176.0)*k4
                                    - (float)(5103.0/18656.0)*k5));
            z = z + h * ((float)(35.0/384.0)*k1 + (float)(500.0/1113.0)*k3
                       + (float)(125.0/192.0)*k4 - (float)(2187.0/6784.0)*k5
                       + (float)(11.0/84.0)*k6);
        }
        if (lane < 16) {
            ztraj[(iv + 1) * 16 + lane] = z;
            zdiff[iv * 16 + lane] = (z - zstart) / dt;
        }
    }
}

// ---------------------------------------------------------------------------
// Decoder: fused 3-layer MLP over 51200 rows. M-tile=16, 256 threads,
// thread micro-tile 2 rows x 16 cols.
// ---------------------------------------------------------------------------
#define GS 516

__global__ __launch_bounds__(256, 2) void dec_kernel(
    const float* __restrict__ ztr,
    const float* __restrict__ w1, const float* __restrict__ b1,
    const float* __restrict__ w2, const float* __restrict__ b2,
    const float* __restrict__ w3, const float* __restrict__ b3,
    float* __restrict__ xhat)
{
    __shared__ __align__(16) float zt[16 * 17];
    __shared__ __align__(16) float g[16 * GS];

    const int t    = threadIdx.x;
    const int blk  = blockIdx.x;
    const int tr   = t >> 5;
    const int tc   = t & 31;
    const int row0 = blk * 16;
    const int r0   = 2 * tr;

    {
        int r = t >> 4, d = t & 15;
        zt[r * 17 + d] = ztr[(row0 + r) * 16 + d];
    }
    __syncthreads();

    // Phase A: g1 = relu(z @ w1 + b1), K=16
    {
        float acc[2][16];
#pragma unroll
        for (int p = 0; p < 2; ++p)
#pragma unroll
            for (int i = 0; i < 16; ++i) acc[p][i] = 0.0f;

#pragma unroll
        for (int k = 0; k < 16; ++k) {
            float a0 = zt[(r0 + 0) * 17 + k];
            float a1 = zt[(r0 + 1) * 17 + k];
            const float4* wr = (const float4*)(w1 + k * 512 + 16 * tc);
#pragma unroll
            for (int u = 0; u < 4; ++u) {
                float4 wv = wr[u];
                acc[0][4*u+0] = fmaf(a0, wv.x, acc[0][4*u+0]);
                acc[0][4*u+1] = fmaf(a0, wv.y, acc[0][4*u+1]);
                acc[0][4*u+2] = fmaf(a0, wv.z, acc[0][4*u+2]);
                acc[0][4*u+3] = fmaf(a0, wv.w, acc[0][4*u+3]);
                acc[1][4*u+0] = fmaf(a1, wv.x, acc[1][4*u+0]);
                acc[1][4*u+1] = fmaf(a1, wv.y, acc[1][4*u+1]);
                acc[1][4*u+2] = fmaf(a1, wv.z, acc[1][4*u+2]);
                acc[1][4*u+3] = fmaf(a1, wv.w, acc[1][4*u+3]);
            }
        }
        const float4* bb = (const float4*)(b1 + 16 * tc);
#pragma unroll
        for (int u = 0; u < 4; ++u) {
            float4 bv = bb[u];
#pragma unroll
            for (int p = 0; p < 2; ++p) {
                g[(r0+p)*GS + 16*tc + 4*u + 0] = fmaxf(acc[p][4*u+0] + bv.x, 0.0f);
                g[(r0+p)*GS + 16*tc + 4*u + 1] = fmaxf(acc[p][4*u+1] + bv.y, 0.0f);
                g[(r0+p)*GS + 16*tc + 4*u + 2] = fmaxf(acc[p][4*u+2] + bv.z, 0.0f);
                g[(r0+p)*GS + 16*tc + 4*u + 3] = fmaxf(acc[p][4*u+3] + bv.w, 0.0f);
            }
        }
    }
    __syncthreads();

    // Phase B: g2 = relu(g1 @ w2 + b2), K=512
    {
        float accB[2][16];
#pragma unroll
        for (int p = 0; p < 2; ++p)
#pragma unroll
            for (int i = 0; i < 16; ++i) accB[p][i] = 0.0f;

        for (int k4 = 0; k4 < 128; ++k4) {
            float4 av0 = *(const float4*)&g[(r0 + 0) * GS + 4 * k4];
            float4 av1 = *(const float4*)&g[(r0 + 1) * GS + 4 * k4];
            float a0[4] = {av0.x, av0.y, av0.z, av0.w};
            float a1[4] = {av1.x, av1.y, av1.z, av1.w};
#pragma unroll
            for (int u = 0; u < 4; ++u) {
                const float4* wr = (const float4*)(w2 + (4 * k4 + u) * 512 + 16 * tc);
#pragma unroll
                for (int q = 0; q < 4; ++q) {
                    float4 wv = wr[q];
                    accB[0][4*q+0] = fmaf(a0[u], wv.x, accB[0][4*q+0]);
                    accB[0][4*q+1] = fmaf(a0[u], wv.y, accB[0][4*q+1]);
                    accB[0][4*q+2] = fmaf(a0[u], wv.z, accB[0][4*q+2]);
                    accB[0][4*q+3] = fmaf(a0[u], wv.w, accB[0][4*q+3]);
                    accB[1][4*q+0] = fmaf(a1[u], wv.x, accB[1][4*q+0]);
                    accB[1][4*q+1] = fmaf(a1[u], wv.y, accB[1][4*q+1]);
                    accB[1][4*q+2] = fmaf(a1[u], wv.z, accB[1][4*q+2]);
                    accB[1][4*q+3] = fmaf(a1[u], wv.w, accB[1][4*q+3]);
                }
            }
        }
        __syncthreads();
        const float4* bb = (const float4*)(b2 + 16 * tc);
#pragma unroll
        for (int u = 0; u < 4; ++u) {
            float4 bv = bb[u];
#pragma unroll
            for (int p = 0; p < 2; ++p) {
                g[(r0+p)*GS + 16*tc + 4*u + 0] = fmaxf(accB[p][4*u+0] + bv.x, 0.0f);
                g[(r0+p)*GS + 16*tc + 4*u + 1] = fmaxf(accB[p][4*u+1] + bv.y, 0.0f);
                g[(r0+p)*GS + 16*tc + 4*u + 2] = fmaxf(accB[p][4*u+2] + bv.z, 0.0f);
                g[(r0+p)*GS + 16*tc + 4*u + 3] = fmaxf(accB[p][4*u+3] + bv.w, 0.0f);
            }
        }
    }
    __syncthreads();

    // Phase C: xhat = g2 @ w3 + b3, N=256, K=512
    {
        float accC[2][8];
#pragma unroll
        for (int p = 0; p < 2; ++p)
#pragma unroll
            for (int i = 0; i < 8; ++i) accC[p][i] = 0.0f;

        for (int k4 = 0; k4 < 128; ++k4) {
            float4 av0 = *(const float4*)&g[(r0 + 0) * GS + 4 * k4];
            float4 av1 = *(const float4*)&g[(r0 + 1) * GS + 4 * k4];
            float a0[4] = {av0.x, av0.y, av0.z, av0.w};
            float a1[4] = {av1.x, av1.y, av1.z, av1.w};
#pragma unroll
            for (int u = 0; u < 4; ++u) {
                const float4* wr = (const float4*)(w3 + (4 * k4 + u) * 256 + 8 * tc);
                float4 w0 = wr[0], w1v = wr[1];
                accC[0][0] = fmaf(a0[u], w0.x,  accC[0][0]);
                accC[0][1] = fmaf(a0[u], w0.y,  accC[0][1]);
                accC[0][2] = fmaf(a0[u], w0.z,  accC[0][2]);
                accC[0][3] = fmaf(a0[u], w0.w,  accC[0][3]);
                accC[0][4] = fmaf(a0[u], w1v.x, accC[0][4]);
                accC[0][5] = fmaf(a0[u], w1v.y, accC[0][5]);
                accC[0][6] = fmaf(a0[u], w1v.z, accC[0][6]);
                accC[0][7] = fmaf(a0[u], w1v.w, accC[0][7]);
                accC[1][0] = fmaf(a1[u], w0.x,  accC[1][0]);
                accC[1][1] = fmaf(a1[u], w0.y,  accC[1][1]);
                accC[1][2] = fmaf(a1[u], w0.z,  accC[1][2]);
                accC[1][3] = fmaf(a1[u], w0.w,  accC[1][3]);
                accC[1][4] = fmaf(a1[u], w1v.x, accC[1][4]);
                accC[1][5] = fmaf(a1[u], w1v.y, accC[1][5]);
                accC[1][6] = fmaf(a1[u], w1v.z, accC[1][6]);
                accC[1][7] = fmaf(a1[u], w1v.w, accC[1][7]);
            }
        }
        const float4* bb = (const float4*)(b3 + 8 * tc);
        float4 bv0 = bb[0], bv1 = bb[1];
#pragma unroll
        for (int p = 0; p < 2; ++p) {
            float4 o0 = make_float4(accC[p][0] + bv0.x, accC[p][1] + bv0.y,
                                    accC[p][2] + bv0.z, accC[p][3] + bv0.w);
            float4 o1 = make_float4(accC[p][4] + bv1.x, accC[p][5] + bv1.y,
                                    accC[p][6] + bv1.z, accC[p][7] + bv1.w);
            float* dst = xhat + (size_t)(row0 + r0 + p) * 256 + 8 * tc;
            *(float4*)(dst)     = o0;
            *(float4*)(dst + 4) = o1;
        }
    }
}

extern "C" void kernel_launch(void* const* d_in, const int* in_sizes, int n_in,
                              void* d_out, int out_size, void* d_ws, size_t ws_size,
                              hipStream_t stream) {
    const float* x_seq  = (const float*)d_in[0];
    const float* tvec   = (const float*)d_in[1];
    const float* eps    = (const float*)d_in[2];
    const float* enc_w1 = (const float*)d_in[3];
    const float* enc_b1 = (const float*)d_in[4];
    const float* enc_w2 = (const float*)d_in[5];
    const float* enc_b2 = (const float*)d_in[6];
    const float* enc_w3 = (const float*)d_in[7];
    const float* enc_b3 = (const float*)d_in[8];
    const float* mu_w   = (const float*)d_in[9];
    const float* mu_b   = (const float*)d_in[10];
    const float* lv_w   = (const float*)d_in[11];
    const float* lv_b   = (const float*)d_in[12];
    const float* ode_w1 = (const float*)d_in[13];
    const float* ode_b1 = (const float*)d_in[14];
    const float* ode_w2 = (const float*)d_in[15];
    const float* ode_b2 = (const float*)d_in[16];
    const float* ode_w3 = (const float*)d_in[17];
    const float* ode_b3 = (const float*)d_in[18];
    const float* ln_g   = (const float*)d_in[19];
    const float* ln_b   = (const float*)d_in[20];
    const float* dec_w1 = (const float*)d_in[21];
    const float* dec_b1 = (const float*)d_in[22];
    const float* dec_w2 = (const float*)d_in[23];
    const float* dec_b2 = (const float*)d_in[24];
    const float* dec_w3 = (const float*)d_in[25];
    const float* dec_b3 = (const float*)d_in[26];
    float* out = (float*)d_out;

    enc_kernel<<<256, 256, 0, stream>>>(x_seq, eps, enc_w1, enc_b1, enc_w2, enc_b2,
                                        enc_w3, enc_b3, mu_w, mu_b, lv_w, lv_b, out);
    ode_kernel<<<256, 64, 0, stream>>>(tvec, ode_w1, ode_b1, ode_w2, ode_b2,
                                       ode_w3, ode_b3, ln_g, ln_b, out);
    dec_kernel<<<3200, 256, 0, stream>>>(out + OFF_ZT, dec_w1, dec_b1, dec_w2, dec_b2,
                                         dec_w3, dec_b3, out);
}

// Round 3
// 23056.427 us; speedup vs baseline: 1.1472x; 1.1472x over previous
//
#include <hip/hip_runtime.h>

// Output layout (flat f32, reference return order):
//   xhat  : B*L*N   = 13,107,200  @ 0
//   mu    : B*D     =      4,096  @ 13,107,200
//   logvar: B*D     =      4,096  @ 13,111,296
//   z_traj: B*L*D   =    819,200  @ 13,115,392
//   zdiff : B*(L-1)*D =  815,104  @ 13,934,592
#define OFF_MU   13107200
#define OFF_LV   13111296
#define OFF_ZT   13115392
#define OFF_ZD   13934592

__device__ __forceinline__ float silu_f(float x) {
    return x * __frcp_rn(1.0f + __expf(-x));
}

// DPP row-rotate add butterfly: after ror8/4/2/1 every lane holds its row-of-16 sum.
template <int CTRL>
__device__ __forceinline__ float dpp_ror_add(float x) {
    int y = __builtin_amdgcn_update_dpp(0, __float_as_int(x), CTRL, 0xF, 0xF, true);
    return x + __int_as_float(y);
}
__device__ __forceinline__ float row_sum16(float x) {
    x = dpp_ror_add<0x128>(x);   // row_ror:8
    x = dpp_ror_add<0x124>(x);   // row_ror:4
    x = dpp_ror_add<0x122>(x);   // row_ror:2
    x = dpp_ror_add<0x121>(x);   // row_ror:1
    return x;
}

// ---------------------------------------------------------------------------
// Encoder: one block per batch row. x0(256) -> 512 -> 256 -> 128 -> mu/lv(16)
// ---------------------------------------------------------------------------
__global__ __launch_bounds__(256) void enc_kernel(
    const float* __restrict__ xseq, const float* __restrict__ eps,
    const float* __restrict__ w1, const float* __restrict__ b1,
    const float* __restrict__ w2, const float* __restrict__ b2,
    const float* __restrict__ w3, const float* __restrict__ b3,
    const float* __restrict__ muw, const float* __restrict__ mub,
    const float* __restrict__ lvw, const float* __restrict__ lvb,
    float* __restrict__ out)
{
    __shared__ float xr[256];
    __shared__ float h1[512];
    __shared__ float h2[256];
    __shared__ float h3[128];

    const int t = threadIdx.x;
    const int b = blockIdx.x;

    xr[t] = xseq[b * (200 * 256) + t];
    __syncthreads();

    {
        float acc0 = b1[t], acc1 = b1[t + 256];
        for (int i = 0; i < 256; ++i) {
            float xv = xr[i];
            acc0 = fmaf(xv, w1[i * 512 + t],       acc0);
            acc1 = fmaf(xv, w1[i * 512 + t + 256], acc1);
        }
        h1[t]       = fmaxf(acc0, 0.0f);
        h1[t + 256] = fmaxf(acc1, 0.0f);
    }
    __syncthreads();

    {
        float acc = b2[t];
        for (int i = 0; i < 512; ++i) acc = fmaf(h1[i], w2[i * 256 + t], acc);
        h2[t] = fmaxf(acc, 0.0f);
    }
    __syncthreads();

    if (t < 128) {
        float acc = b3[t];
        for (int i = 0; i < 256; ++i) acc = fmaf(h2[i], w3[i * 128 + t], acc);
        h3[t] = fmaxf(acc, 0.0f);
    }
    __syncthreads();

    if (t < 16) {
        float mu = mub[t], lv = lvb[t];
        for (int i = 0; i < 128; ++i) {
            float hv = h3[i];
            mu = fmaf(hv, muw[i * 16 + t], mu);
            lv = fmaf(hv, lvw[i * 16 + t], lv);
        }
        out[OFF_MU + b * 16 + t] = mu;
        out[OFF_LV + b * 16 + t] = lv;
        float z0 = mu + __expf(0.5f * lv) * eps[b * 16 + t];
        out[OFF_ZT + b * 3200 + t] = z0;
    }
}

// ---------------------------------------------------------------------------
// ODE integrator: ONE 64-lane WAVE per batch element (256 blocks x 64 thr).
// amdgpu_waves_per_eu(1,1): pin 1 wave/EU so the allocator gets the full 512
// VGPR budget (R2 failed: allocator targeted 3 waves/EU -> 168 VGPRs -> the
// entire w2 array spilled to scratch; 24ms). ALL register arrays statically
// indexed; w3 pre-permuted at load so the staggered LDS read keeps
// compile-time register indices.
// ---------------------------------------------------------------------------
__global__
__attribute__((amdgpu_flat_work_group_size(64, 64)))
__attribute__((amdgpu_waves_per_eu(1, 1)))
void ode_kernel(
    const float* __restrict__ tvec,
    const float* __restrict__ ow1, const float* __restrict__ ob1,
    const float* __restrict__ ow2, const float* __restrict__ ob2,
    const float* __restrict__ ow3, const float* __restrict__ ob3,
    const float* __restrict__ lng, const float* __restrict__ lnb,
    float* __restrict__ out)
{
    __shared__ __align__(16) float zargS[16];
    __shared__ __align__(16) float a1s[128];
    __shared__ __align__(16) float a2s[128];
    __shared__ __align__(16) float p3s[64];   // [d][r] at index d*4+r

    const int lane = threadIdx.x;
    const int b    = blockIdx.x;
    const int r    = lane >> 4;
    const int d    = lane & 15;
    const int j0   = lane;
    const int j1   = lane + 64;

    // ---- register-resident weights (all statically indexed) ----
    float4 w1q0[4], w1q1[4];
#pragma unroll
    for (int q = 0; q < 4; ++q) {
        w1q0[q] = make_float4(ow1[(4*q+0)*128 + j0], ow1[(4*q+1)*128 + j0],
                              ow1[(4*q+2)*128 + j0], ow1[(4*q+3)*128 + j0]);
        w1q1[q] = make_float4(ow1[(4*q+0)*128 + j1], ow1[(4*q+1)*128 + j1],
                              ow1[(4*q+2)*128 + j1], ow1[(4*q+3)*128 + j1]);
    }
    float4 w2q0[32], w2q1[32];
#pragma unroll
    for (int q = 0; q < 32; ++q) {
        w2q0[q] = make_float4(ow2[(4*q+0)*128 + j0], ow2[(4*q+1)*128 + j0],
                              ow2[(4*q+2)*128 + j0], ow2[(4*q+3)*128 + j0]);
        w2q1[q] = make_float4(ow2[(4*q+0)*128 + j1], ow2[(4*q+1)*128 + j1],
                              ow2[(4*q+2)*128 + j1], ow2[(4*q+3)*128 + j1]);
    }
    // w3 pre-permuted: inner-loop step t uses K-chunk i=(t+2r)&7 of this
    // lane's K-range [32r,32r+32). Permutation applied HERE so the loop
    // indexes w3p with compile-time t.
    float4 w3p[8];
#pragma unroll
    for (int t = 0; t < 8; ++t) {
        int i = (t + 2 * r) & 7;
        int k0 = 32 * r + 4 * i;
        w3p[t] = make_float4(ow3[(k0+0)*16 + d], ow3[(k0+1)*16 + d],
                             ow3[(k0+2)*16 + d], ow3[(k0+3)*16 + d]);
    }

    const float b1j0 = ob1[j0], b1j1 = ob1[j1];
    const float b2j0 = ob2[j0], b2j1 = ob2[j1];
    const float b3d  = ob3[d];
    const float lngd = lng[d];
    const float lnbd = lnb[d];

    float* ztraj = out + OFF_ZT + b * 3200;   // [200][16]
    float* zdiff = out + OFF_ZD + b * 3184;   // [199][16]

    float z = ztraj[d];   // broadcast read; replicated across the 4 rows

    auto feval = [&](float za) -> float {
        if (lane < 16) zargS[lane] = za;
        __syncthreads();   // single-wave: lowers to s_waitcnt, no s_barrier
        const float4* Z4 = (const float4*)zargS;
        float4 Z0 = Z4[0], Z1 = Z4[1], Z2 = Z4[2], Z3 = Z4[3];

        // L1: 2 columns, K=16 (fully static)
        float acc0 = b1j0, acc1 = b1j1;
        acc0 = fmaf(Z0.x, w1q0[0].x, acc0); acc1 = fmaf(Z0.x, w1q1[0].x, acc1);
        acc0 = fmaf(Z0.y, w1q0[0].y, acc0); acc1 = fmaf(Z0.y, w1q1[0].y, acc1);
        acc0 = fmaf(Z0.z, w1q0[0].z, acc0); acc1 = fmaf(Z0.z, w1q1[0].z, acc1);
        acc0 = fmaf(Z0.w, w1q0[0].w, acc0); acc1 = fmaf(Z0.w, w1q1[0].w, acc1);
        acc0 = fmaf(Z1.x, w1q0[1].x, acc0); acc1 = fmaf(Z1.x, w1q1[1].x, acc1);
        acc0 = fmaf(Z1.y, w1q0[1].y, acc0); acc1 = fmaf(Z1.y, w1q1[1].y, acc1);
        acc0 = fmaf(Z1.z, w1q0[1].z, acc0); acc1 = fmaf(Z1.z, w1q1[1].z, acc1);
        acc0 = fmaf(Z1.w, w1q0[1].w, acc0); acc1 = fmaf(Z1.w, w1q1[1].w, acc1);
        acc0 = fmaf(Z2.x, w1q0[2].x, acc0); acc1 = fmaf(Z2.x, w1q1[2].x, acc1);
        acc0 = fmaf(Z2.y, w1q0[2].y, acc0); acc1 = fmaf(Z2.y, w1q1[2].y, acc1);
        acc0 = fmaf(Z2.z, w1q0[2].z, acc0); acc1 = fmaf(Z2.z, w1q1[2].z, acc1);
        acc0 = fmaf(Z2.w, w1q0[2].w, acc0); acc1 = fmaf(Z2.w, w1q1[2].w, acc1);
        acc0 = fmaf(Z3.x, w1q0[3].x, acc0); acc1 = fmaf(Z3.x, w1q1[3].x, acc1);
        acc0 = fmaf(Z3.y, w1q0[3].y, acc0); acc1 = fmaf(Z3.y, w1q1[3].y, acc1);
        acc0 = fmaf(Z3.z, w1q0[3].z, acc0); acc1 = fmaf(Z3.z, w1q1[3].z, acc1);
        acc0 = fmaf(Z3.w, w1q0[3].w, acc0); acc1 = fmaf(Z3.w, w1q1[3].w, acc1);
        a1s[j0] = silu_f(acc0);
        a1s[j1] = silu_f(acc1);
        __syncthreads();

        // L2: 2 columns, K=128; 2 accumulation chains per column.
        float c0a = 0.0f, c0b = 0.0f, c1a = 0.0f, c1b = 0.0f;
        const float4* A4 = (const float4*)a1s;
#pragma unroll
        for (int p = 0; p < 16; ++p) {
            float4 a = A4[2 * p];
            float4 bq = A4[2 * p + 1];
            float4 u0 = w2q0[2 * p], u1 = w2q0[2 * p + 1];
            float4 v0 = w2q1[2 * p], v1 = w2q1[2 * p + 1];
            c0a = fmaf(a.x,  u0.x, c0a); c1a = fmaf(a.x,  v0.x, c1a);
            c0a = fmaf(a.y,  u0.y, c0a); c1a = fmaf(a.y,  v0.y, c1a);
            c0a = fmaf(a.z,  u0.z, c0a); c1a = fmaf(a.z,  v0.z, c1a);
            c0a = fmaf(a.w,  u0.w, c0a); c1a = fmaf(a.w,  v0.w, c1a);
            c0b = fmaf(bq.x, u1.x, c0b); c1b = fmaf(bq.x, v1.x, c1b);
            c0b = fmaf(bq.y, u1.y, c0b); c1b = fmaf(bq.y, v1.y, c1b);
            c0b = fmaf(bq.z, u1.z, c0b); c1b = fmaf(bq.z, v1.z, c1b);
            c0b = fmaf(bq.w, u1.w, c0b); c1b = fmaf(bq.w, v1.w, c1b);
        }
        a2s[j0] = silu_f(c0a + c0b + b2j0);
        a2s[j1] = silu_f(c1a + c1b + b2j1);
        __syncthreads();

        // L3 partial: lane (r,d) covers k in [32r,32r+32); staggered LDS reads
        // (i=(t+2r)&7) keep the 4 rows on disjoint bank groups; w3p is
        // pre-permuted so register indices stay compile-time.
        float pA = 0.0f, pB = 0.0f;
        const float4* B4 = (const float4*)a2s;
#pragma unroll
        for (int t = 0; t < 8; ++t) {
            int i = (t + 2 * r) & 7;
            float4 a = B4[r * 8 + i];
            float4 w = w3p[t];
            pA = fmaf(a.x, w.x, pA);
            pB = fmaf(a.y, w.y, pB);
            pA = fmaf(a.z, w.z, pA);
            pB = fmaf(a.w, w.w, pB);
        }
        p3s[d * 4 + r] = pA + pB;
        __syncthreads();
        float4 pv = ((const float4*)p3s)[d];
        float dz = pv.x + pv.y + pv.z + pv.w + b3d;

        // LayerNorm over the 16 dims (intra-row DPP reduction)
        float m  = row_sum16(dz) * 0.0625f;
        float df = dz - m;
        float v  = row_sum16(df * df) * 0.0625f;
        return df * rsqrtf(v + 1e-5f) * lngd + lnbd;
    };

    for (int iv = 0; iv < 199; ++iv) {
        const float dt = tvec[iv + 1] - tvec[iv];
        const float h  = dt * 0.125f;
        const float zstart = z;
        for (int s = 0; s < 8; ++s) {
            float k1 = feval(z);
            float k2 = feval(z + h * (0.2f * k1));
            float k3 = feval(z + h * ((float)(3.0/40.0)*k1 + (float)(9.0/40.0)*k2));
            float k4 = feval(z + h * ((float)(44.0/45.0)*k1 - (float)(56.0/15.0)*k2
                                    + (float)(32.0/9.0)*k3));
            float k5 = feval(z + h * ((float)(19372.0/6561.0)*k1 - (float)(25360.0/2187.0)*k2
                                    + (float)(64448.0/6561.0)*k3 - (float)(212.0/729.0)*k4));
            float k6 = feval(z + h * ((float)(9017.0/3168.0)*k1 - (float)(355.0/33.0)*k2
                                    + (float)(46732.0/5247.0)*k3 + (float)(49.0/176.0)*k4
                                    - (float)(5103.0/18656.0)*k5));
            z = z + h * ((float)(35.0/384.0)*k1 + (float)(500.0/1113.0)*k3
                       + (float)(125.0/192.0)*k4 - (float)(2187.0/6784.0)*k5
                       + (float)(11.0/84.0)*k6);
        }
        if (lane < 16) {
            ztraj[(iv + 1) * 16 + lane] = z;
            zdiff[iv * 16 + lane] = (z - zstart) / dt;
        }
    }
}

// ---------------------------------------------------------------------------
// Decoder: fused 3-layer MLP over 51200 rows. M-tile=16, 256 threads,
// thread micro-tile 2 rows x 16 cols.
// ---------------------------------------------------------------------------
#define GS 516

__global__ __launch_bounds__(256, 2) void dec_kernel(
    const float* __restrict__ ztr,
    const float* __restrict__ w1, const float* __restrict__ b1,
    const float* __restrict__ w2, const float* __restrict__ b2,
    const float* __restrict__ w3, const float* __restrict__ b3,
    float* __restrict__ xhat)
{
    __shared__ __align__(16) float zt[16 * 17];
    __shared__ __align__(16) float g[16 * GS];

    const int t    = threadIdx.x;
    const int blk  = blockIdx.x;
    const int tr   = t >> 5;
    const int tc   = t & 31;
    const int row0 = blk * 16;
    const int r0   = 2 * tr;

    {
        int r = t >> 4, d = t & 15;
        zt[r * 17 + d] = ztr[(row0 + r) * 16 + d];
    }
    __syncthreads();

    // Phase A: g1 = relu(z @ w1 + b1), K=16
    {
        float acc[2][16];
#pragma unroll
        for (int p = 0; p < 2; ++p)
#pragma unroll
            for (int i = 0; i < 16; ++i) acc[p][i] = 0.0f;

#pragma unroll
        for (int k = 0; k < 16; ++k) {
            float a0 = zt[(r0 + 0) * 17 + k];
            float a1 = zt[(r0 + 1) * 17 + k];
            const float4* wr = (const float4*)(w1 + k * 512 + 16 * tc);
#pragma unroll
            for (int u = 0; u < 4; ++u) {
                float4 wv = wr[u];
                acc[0][4*u+0] = fmaf(a0, wv.x, acc[0][4*u+0]);
                acc[0][4*u+1] = fmaf(a0, wv.y, acc[0][4*u+1]);
                acc[0][4*u+2] = fmaf(a0, wv.z, acc[0][4*u+2]);
                acc[0][4*u+3] = fmaf(a0, wv.w, acc[0][4*u+3]);
                acc[1][4*u+0] = fmaf(a1, wv.x, acc[1][4*u+0]);
                acc[1][4*u+1] = fmaf(a1, wv.y, acc[1][4*u+1]);
                acc[1][4*u+2] = fmaf(a1, wv.z, acc[1][4*u+2]);
                acc[1][4*u+3] = fmaf(a1, wv.w, acc[1][4*u+3]);
            }
        }
        const float4* bb = (const float4*)(b1 + 16 * tc);
#pragma unroll
        for (int u = 0; u < 4; ++u) {
            float4 bv = bb[u];
#pragma unroll
            for (int p = 0; p < 2; ++p) {
                g[(r0+p)*GS + 16*tc + 4*u + 0] = fmaxf(acc[p][4*u+0] + bv.x, 0.0f);
                g[(r0+p)*GS + 16*tc + 4*u + 1] = fmaxf(acc[p][4*u+1] + bv.y, 0.0f);
                g[(r0+p)*GS + 16*tc + 4*u + 2] = fmaxf(acc[p][4*u+2] + bv.z, 0.0f);
                g[(r0+p)*GS + 16*tc + 4*u + 3] = fmaxf(acc[p][4*u+3] + bv.w, 0.0f);
            }
        }
    }
    __syncthreads();

    // Phase B: g2 = relu(g1 @ w2 + b2), K=512
    {
        float accB[2][16];
#pragma unroll
        for (int p = 0; p < 2; ++p)
#pragma unroll
            for (int i = 0; i < 16; ++i) accB[p][i] = 0.0f;

        for (int k4 = 0; k4 < 128; ++k4) {
            float4 av0 = *(const float4*)&g[(r0 + 0) * GS + 4 * k4];
            float4 av1 = *(const float4*)&g[(r0 + 1) * GS + 4 * k4];
            float a0[4] = {av0.x, av0.y, av0.z, av0.w};
            float a1[4] = {av1.x, av1.y, av1.z, av1.w};
#pragma unroll
            for (int u = 0; u < 4; ++u) {
                const float4* wr = (const float4*)(w2 + (4 * k4 + u) * 512 + 16 * tc);
#pragma unroll
                for (int q = 0; q < 4; ++q) {
                    float4 wv = wr[q];
                    accB[0][4*q+0] = fmaf(a0[u], wv.x, accB[0][4*q+0]);
                    accB[0][4*q+1] = fmaf(a0[u], wv.y, accB[0][4*q+1]);
                    accB[0][4*q+2] = fmaf(a0[u], wv.z, accB[0][4*q+2]);
                    accB[0][4*q+3] = fmaf(a0[u], wv.w, accB[0][4*q+3]);
                    accB[1][4*q+0] = fmaf(a1[u], wv.x, accB[1][4*q+0]);
                    accB[1][4*q+1] = fmaf(a1[u], wv.y, accB[1][4*q+1]);
                    accB[1][4*q+2] = fmaf(a1[u], wv.z, accB[1][4*q+2]);
                    accB[1][4*q+3] = fmaf(a1[u], wv.w, accB[1][4*q+3]);
                }
            }
        }
        __syncthreads();
        const float4* bb = (const float4*)(b2 + 16 * tc);
#pragma unroll
        for (int u = 0; u < 4; ++u) {
            float4 bv = bb[u];
#pragma unroll
            for (int p = 0; p < 2; ++p) {
                g[(r0+p)*GS + 16*tc + 4*u + 0] = fmaxf(accB[p][4*u+0] + bv.x, 0.0f);
                g[(r0+p)*GS + 16*tc + 4*u + 1] = fmaxf(accB[p][4*u+1] + bv.y, 0.0f);
                g[(r0+p)*GS + 16*tc + 4*u + 2] = fmaxf(accB[p][4*u+2] + bv.z, 0.0f);
                g[(r0+p)*GS + 16*tc + 4*u + 3] = fmaxf(accB[p][4*u+3] + bv.w, 0.0f);
            }
        }
    }
    __syncthreads();

    // Phase C: xhat = g2 @ w3 + b3, N=256, K=512
    {
        float accC[2][8];
#pragma unroll
        for (int p = 0; p < 2; ++p)
#pragma unroll
            for (int i = 0; i < 8; ++i) accC[p][i] = 0.0f;

        for (int k4 = 0; k4 < 128; ++k4) {
            float4 av0 = *(const float4*)&g[(r0 + 0) * GS + 4 * k4];
            float4 av1 = *(const float4*)&g[(r0 + 1) * GS + 4 * k4];
            float a0[4] = {av0.x, av0.y, av0.z, av0.w};
            float a1[4] = {av1.x, av1.y, av1.z, av1.w};
#pragma unroll
            for (int u = 0; u < 4; ++u) {
                const float4* wr = (const float4*)(w3 + (4 * k4 + u) * 256 + 8 * tc);
                float4 w0 = wr[0], w1v = wr[1];
                accC[0][0] = fmaf(a0[u], w0.x,  accC[0][0]);
                accC[0][1] = fmaf(a0[u], w0.y,  accC[0][1]);
                accC[0][2] = fmaf(a0[u], w0.z,  accC[0][2]);
                accC[0][3] = fmaf(a0[u], w0.w,  accC[0][3]);
                accC[0][4] = fmaf(a0[u], w1v.x, accC[0][4]);
                accC[0][5] = fmaf(a0[u], w1v.y, accC[0][5]);
                accC[0][6] = fmaf(a0[u], w1v.z, accC[0][6]);
                accC[0][7] = fmaf(a0[u], w1v.w, accC[0][7]);
                accC[1][0] = fmaf(a1[u], w0.x,  accC[1][0]);
                accC[1][1] = fmaf(a1[u], w0.y,  accC[1][1]);
                accC[1][2] = fmaf(a1[u], w0.z,  accC[1][2]);
                accC[1][3] = fmaf(a1[u], w0.w,  accC[1][3]);
                accC[1][4] = fmaf(a1[u], w1v.x, accC[1][4]);
                accC[1][5] = fmaf(a1[u], w1v.y, accC[1][5]);
                accC[1][6] = fmaf(a1[u], w1v.z, accC[1][6]);
                accC[1][7] = fmaf(a1[u], w1v.w, accC[1][7]);
            }
        }
        const float4* bb = (const float4*)(b3 + 8 * tc);
        float4 bv0 = bb[0], bv1 = bb[1];
#pragma unroll
        for (int p = 0; p < 2; ++p) {
            float4 o0 = make_float4(accC[p][0] + bv0.x, accC[p][1] + bv0.y,
                                    accC[p][2] + bv0.z, accC[p][3] + bv0.w);
            float4 o1 = make_float4(accC[p][4] + bv1.x, accC[p][5] + bv1.y,
                                    accC[p][6] + bv1.z, accC[p][7] + bv1.w);
            float* dst = xhat + (size_t)(row0 + r0 + p) * 256 + 8 * tc;
            *(float4*)(dst)     = o0;
            *(float4*)(dst + 4) = o1;
        }
    }
}

extern "C" void kernel_launch(void* const* d_in, const int* in_sizes, int n_in,
                              void* d_out, int out_size, void* d_ws, size_t ws_size,
                              hipStream_t stream) {
    const float* x_seq  = (const float*)d_in[0];
    const float* tvec   = (const float*)d_in[1];
    const float* eps    = (const float*)d_in[2];
    const float* enc_w1 = (const float*)d_in[3];
    const float* enc_b1 = (const float*)d_in[4];
    const float* enc_w2 = (const float*)d_in[5];
    const float* enc_b2 = (const float*)d_in[6];
    const float* enc_w3 = (const float*)d_in[7];
    const float* enc_b3 = (const float*)d_in[8];
    const float* mu_w   = (const float*)d_in[9];
    const float* mu_b   = (const float*)d_in[10];
    const float* lv_w   = (const float*)d_in[11];
    const float* lv_b   = (const float*)d_in[12];
    const float* ode_w1 = (const float*)d_in[13];
    const float* ode_b1 = (const float*)d_in[14];
    const float* ode_w2 = (const float*)d_in[15];
    const float* ode_b2 = (const float*)d_in[16];
    const float* ode_w3 = (const float*)d_in[17];
    const float* ode_b3 = (const float*)d_in[18];
    const float* ln_g   = (const float*)d_in[19];
    const float* ln_b   = (const float*)d_in[20];
    const float* dec_w1 = (const float*)d_in[21];
    const float* dec_b1 = (const float*)d_in[22];
    const float* dec_w2 = (const float*)d_in[23];
    const float* dec_b2 = (const float*)d_in[24];
    const float* dec_w3 = (const float*)d_in[25];
    const float* dec_b3 = (const float*)d_in[26];
    float* out = (float*)d_out;

    enc_kernel<<<256, 256, 0, stream>>>(x_seq, eps, enc_w1, enc_b1, enc_w2, enc_b2,
                                        enc_w3, enc_b3, mu_w, mu_b, lv_w, lv_b, out);
    ode_kernel<<<256, 64, 0, stream>>>(tvec, ode_w1, ode_b1, ode_w2, ode_b2,
                                       ode_w3, ode_b3, ln_g, ln_b, out);
    dec_kernel<<<3200, 256, 0, stream>>>(out + OFF_ZT, dec_w1, dec_b1, dec_w2, dec_b2,
                                         dec_w3, dec_b3, out);
}

// Round 4
// 16566.579 us; speedup vs baseline: 1.5966x; 1.3917x over previous
//
#include <hip/hip_runtime.h>

// Output layout (flat f32, reference return order):
//   xhat  : B*L*N   = 13,107,200  @ 0
//   mu    : B*D     =      4,096  @ 13,107,200
//   logvar: B*D     =      4,096  @ 13,111,296
//   z_traj: B*L*D   =    819,200  @ 13,115,392
//   zdiff : B*(L-1)*D =  815,104  @ 13,934,592
#define OFF_MU   13107200
#define OFF_LV   13111296
#define OFF_ZT   13115392
#define OFF_ZD   13934592

__device__ __forceinline__ float silu_f(float x) {
    return x * __frcp_rn(1.0f + __expf(-x));
}

// DPP row-rotate add butterfly: after ror8/4/2/1 every lane holds its row-of-16 sum.
template <int CTRL>
__device__ __forceinline__ float dpp_ror_add(float x) {
    int y = __builtin_amdgcn_update_dpp(0, __float_as_int(x), CTRL, 0xF, 0xF, true);
    return x + __int_as_float(y);
}
__device__ __forceinline__ float row_sum16(float x) {
    x = dpp_ror_add<0x128>(x);   // row_ror:8
    x = dpp_ror_add<0x124>(x);   // row_ror:4
    x = dpp_ror_add<0x122>(x);   // row_ror:2
    x = dpp_ror_add<0x121>(x);   // row_ror:1
    return x;
}

// ---------------------------------------------------------------------------
// Encoder: one block per batch row. x0(256) -> 512 -> 256 -> 128 -> mu/lv(16)
// ---------------------------------------------------------------------------
__global__ __launch_bounds__(256) void enc_kernel(
    const float* __restrict__ xseq, const float* __restrict__ eps,
    const float* __restrict__ w1, const float* __restrict__ b1,
    const float* __restrict__ w2, const float* __restrict__ b2,
    const float* __restrict__ w3, const float* __restrict__ b3,
    const float* __restrict__ muw, const float* __restrict__ mub,
    const float* __restrict__ lvw, const float* __restrict__ lvb,
    float* __restrict__ out)
{
    __shared__ float xr[256];
    __shared__ float h1[512];
    __shared__ float h2[256];
    __shared__ float h3[128];

    const int t = threadIdx.x;
    const int b = blockIdx.x;

    xr[t] = xseq[b * (200 * 256) + t];
    __syncthreads();

    {
        float acc0 = b1[t], acc1 = b1[t + 256];
        for (int i = 0; i < 256; ++i) {
            float xv = xr[i];
            acc0 = fmaf(xv, w1[i * 512 + t],       acc0);
            acc1 = fmaf(xv, w1[i * 512 + t + 256], acc1);
        }
        h1[t]       = fmaxf(acc0, 0.0f);
        h1[t + 256] = fmaxf(acc1, 0.0f);
    }
    __syncthreads();

    {
        float acc = b2[t];
        for (int i = 0; i < 512; ++i) acc = fmaf(h1[i], w2[i * 256 + t], acc);
        h2[t] = fmaxf(acc, 0.0f);
    }
    __syncthreads();

    if (t < 128) {
        float acc = b3[t];
        for (int i = 0; i < 256; ++i) acc = fmaf(h2[i], w3[i * 128 + t], acc);
        h3[t] = fmaxf(acc, 0.0f);
    }
    __syncthreads();

    if (t < 16) {
        float mu = mub[t], lv = lvb[t];
        for (int i = 0; i < 128; ++i) {
            float hv = h3[i];
            mu = fmaf(hv, muw[i * 16 + t], mu);
            lv = fmaf(hv, lvw[i * 16 + t], lv);
        }
        out[OFF_MU + b * 16 + t] = mu;
        out[OFF_LV + b * 16 + t] = lv;
        float z0 = mu + __expf(0.5f * lv) * eps[b * 16 + t];
        out[OFF_ZT + b * 3200 + t] = z0;
    }
}

// ---------------------------------------------------------------------------
// ODE integrator: ONE 64-lane WAVE per batch element (256 blocks x 64 thr).
// R3 lesson: arch-VGPR cap is 256/wave — 256 floats of w2 per lane cannot
// live in registers. Split: w2 column j0 in registers (128 VGPRs, statically
// indexed), column j1 in LDS (contiguous float4-per-lane pattern, ~12 cyc
// wave-wide b128 reads overlapping the fma stream). w3 also in LDS
// (pre-permuted per lane). Cross-row reduction via shfl_xor instead of an
// LDS round-trip. All state (z, k1..k6) lane-replicated; 3 waitcnt-only
// syncs per feval (single wave => no s_barrier).
// ---------------------------------------------------------------------------
__global__
__attribute__((amdgpu_flat_work_group_size(64, 64)))
__attribute__((amdgpu_waves_per_eu(1, 1)))
void ode_kernel(
    const float* __restrict__ tvec,
    const float* __restrict__ ow1, const float* __restrict__ ob1,
    const float* __restrict__ ow2, const float* __restrict__ ob2,
    const float* __restrict__ ow3, const float* __restrict__ ob3,
    const float* __restrict__ lng, const float* __restrict__ lnb,
    float* __restrict__ out)
{
    __shared__ __align__(16) float  zargS[16];
    __shared__ __align__(16) float  a1s[128];
    __shared__ __align__(16) float  a2s[128];
    __shared__ __align__(16) float4 w2L[32 * 64];   // [p][lane]: col j1, k=4p..4p+3
    __shared__ __align__(16) float4 w3L[8 * 64];    // [t][lane]: pre-permuted

    const int lane = threadIdx.x;
    const int b    = blockIdx.x;
    const int r    = lane >> 4;
    const int d    = lane & 15;
    const int j0   = lane;
    const int j1   = lane + 64;

    // ---- register-resident weights: w1 (both cols) + w2 col j0 ----
    float4 w1q0[4], w1q1[4];
#pragma unroll
    for (int q = 0; q < 4; ++q) {
        w1q0[q] = make_float4(ow1[(4*q+0)*128 + j0], ow1[(4*q+1)*128 + j0],
                              ow1[(4*q+2)*128 + j0], ow1[(4*q+3)*128 + j0]);
        w1q1[q] = make_float4(ow1[(4*q+0)*128 + j1], ow1[(4*q+1)*128 + j1],
                              ow1[(4*q+2)*128 + j1], ow1[(4*q+3)*128 + j1]);
    }
    float4 w2q0[32];
#pragma unroll
    for (int q = 0; q < 32; ++q) {
        w2q0[q] = make_float4(ow2[(4*q+0)*128 + j0], ow2[(4*q+1)*128 + j0],
                              ow2[(4*q+2)*128 + j0], ow2[(4*q+3)*128 + j0]);
    }
    // ---- LDS-resident weights: w2 col j1, w3 (pre-permuted stagger) ----
#pragma unroll
    for (int q = 0; q < 32; ++q) {
        w2L[q * 64 + lane] = make_float4(ow2[(4*q+0)*128 + j1], ow2[(4*q+1)*128 + j1],
                                         ow2[(4*q+2)*128 + j1], ow2[(4*q+3)*128 + j1]);
    }
#pragma unroll
    for (int t = 0; t < 8; ++t) {
        int i  = (t + 2 * r) & 7;          // stagger: rows hit disjoint banks
        int k0 = 32 * r + 4 * i;
        w3L[t * 64 + lane] = make_float4(ow3[(k0+0)*16 + d], ow3[(k0+1)*16 + d],
                                         ow3[(k0+2)*16 + d], ow3[(k0+3)*16 + d]);
    }

    const float b1j0 = ob1[j0], b1j1 = ob1[j1];
    const float b2j0 = ob2[j0], b2j1 = ob2[j1];
    const float b3d  = ob3[d];
    const float lngd = lng[d];
    const float lnbd = lnb[d];

    float* ztraj = out + OFF_ZT + b * 3200;   // [200][16]
    float* zdiff = out + OFF_ZD + b * 3184;   // [199][16]

    float z = ztraj[d];   // broadcast read; replicated across the 4 rows
    __syncthreads();

    auto feval = [&](float za) -> float {
        if (lane < 16) zargS[lane] = za;
        __syncthreads();   // single-wave: lowers to s_waitcnt, no s_barrier
        const float4* Z4 = (const float4*)zargS;
        float4 Z0 = Z4[0], Z1 = Z4[1], Z2 = Z4[2], Z3 = Z4[3];

        // L1: 2 columns, K=16 (register weights, fully static)
        float acc0 = b1j0, acc1 = b1j1;
        acc0 = fmaf(Z0.x, w1q0[0].x, acc0); acc1 = fmaf(Z0.x, w1q1[0].x, acc1);
        acc0 = fmaf(Z0.y, w1q0[0].y, acc0); acc1 = fmaf(Z0.y, w1q1[0].y, acc1);
        acc0 = fmaf(Z0.z, w1q0[0].z, acc0); acc1 = fmaf(Z0.z, w1q1[0].z, acc1);
        acc0 = fmaf(Z0.w, w1q0[0].w, acc0); acc1 = fmaf(Z0.w, w1q1[0].w, acc1);
        acc0 = fmaf(Z1.x, w1q0[1].x, acc0); acc1 = fmaf(Z1.x, w1q1[1].x, acc1);
        acc0 = fmaf(Z1.y, w1q0[1].y, acc0); acc1 = fmaf(Z1.y, w1q1[1].y, acc1);
        acc0 = fmaf(Z1.z, w1q0[1].z, acc0); acc1 = fmaf(Z1.z, w1q1[1].z, acc1);
        acc0 = fmaf(Z1.w, w1q0[1].w, acc0); acc1 = fmaf(Z1.w, w1q1[1].w, acc1);
        acc0 = fmaf(Z2.x, w1q0[2].x, acc0); acc1 = fmaf(Z2.x, w1q1[2].x, acc1);
        acc0 = fmaf(Z2.y, w1q0[2].y, acc0); acc1 = fmaf(Z2.y, w1q1[2].y, acc1);
        acc0 = fmaf(Z2.z, w1q0[2].z, acc0); acc1 = fmaf(Z2.z, w1q1[2].z, acc1);
        acc0 = fmaf(Z2.w, w1q0[2].w, acc0); acc1 = fmaf(Z2.w, w1q1[2].w, acc1);
        acc0 = fmaf(Z3.x, w1q0[3].x, acc0); acc1 = fmaf(Z3.x, w1q1[3].x, acc1);
        acc0 = fmaf(Z3.y, w1q0[3].y, acc0); acc1 = fmaf(Z3.y, w1q1[3].y, acc1);
        acc0 = fmaf(Z3.z, w1q0[3].z, acc0); acc1 = fmaf(Z3.z, w1q1[3].z, acc1);
        acc0 = fmaf(Z3.w, w1q0[3].w, acc0); acc1 = fmaf(Z3.w, w1q1[3].w, acc1);
        a1s[j0] = silu_f(acc0);
        a1s[j1] = silu_f(acc1);
        __syncthreads();

        // L2: col j0 from registers, col j1 from LDS; 2 chains per column.
        float c0a = 0.0f, c0b = 0.0f, c1a = 0.0f, c1b = 0.0f;
        const float4* A4 = (const float4*)a1s;
#pragma unroll
        for (int p = 0; p < 16; ++p) {
            float4 a  = A4[2 * p];               // broadcast
            float4 bq = A4[2 * p + 1];           // broadcast
            float4 u0 = w2q0[2 * p], u1 = w2q0[2 * p + 1];
            float4 v0 = w2L[(2 * p) * 64 + lane];
            float4 v1 = w2L[(2 * p + 1) * 64 + lane];
            c0a = fmaf(a.x,  u0.x, c0a); c1a = fmaf(a.x,  v0.x, c1a);
            c0a = fmaf(a.y,  u0.y, c0a); c1a = fmaf(a.y,  v0.y, c1a);
            c0a = fmaf(a.z,  u0.z, c0a); c1a = fmaf(a.z,  v0.z, c1a);
            c0a = fmaf(a.w,  u0.w, c0a); c1a = fmaf(a.w,  v0.w, c1a);
            c0b = fmaf(bq.x, u1.x, c0b); c1b = fmaf(bq.x, v1.x, c1b);
            c0b = fmaf(bq.y, u1.y, c0b); c1b = fmaf(bq.y, v1.y, c1b);
            c0b = fmaf(bq.z, u1.z, c0b); c1b = fmaf(bq.z, v1.z, c1b);
            c0b = fmaf(bq.w, u1.w, c0b); c1b = fmaf(bq.w, v1.w, c1b);
        }
        a2s[j0] = silu_f(c0a + c0b + b2j0);
        a2s[j1] = silu_f(c1a + c1b + b2j1);
        __syncthreads();

        // L3 partial: lane (r,d) covers k in [32r,32r+32); staggered a2 reads
        // (broadcast within each 16-lane row, disjoint banks across rows);
        // w3L pre-permuted to match.
        float pA = 0.0f, pB = 0.0f;
        const float4* B4 = (const float4*)a2s;
#pragma unroll
        for (int t = 0; t < 8; ++t) {
            int i = (t + 2 * r) & 7;
            float4 a = B4[r * 8 + i];
            float4 w = w3L[t * 64 + lane];
            pA = fmaf(a.x, w.x, pA);
            pB = fmaf(a.y, w.y, pB);
            pA = fmaf(a.z, w.z, pA);
            pB = fmaf(a.w, w.w, pB);
        }
        // cross-row reduce (lanes d, d+16, d+32, d+48) without LDS round-trip
        float part = pA + pB;
        part += __shfl_xor(part, 16);
        part += __shfl_xor(part, 32);
        float dz = part + b3d;

        // LayerNorm over the 16 dims (intra-row DPP reduction, all lanes)
        float m  = row_sum16(dz) * 0.0625f;
        float df = dz - m;
        float v  = row_sum16(df * df) * 0.0625f;
        return df * rsqrtf(v + 1e-5f) * lngd + lnbd;
    };

    for (int iv = 0; iv < 199; ++iv) {
        const float dt = tvec[iv + 1] - tvec[iv];
        const float h  = dt * 0.125f;
        const float zstart = z;
        for (int s = 0; s < 8; ++s) {
            float k1 = feval(z);
            float k2 = feval(z + h * (0.2f * k1));
            float k3 = feval(z + h * ((float)(3.0/40.0)*k1 + (float)(9.0/40.0)*k2));
            float k4 = feval(z + h * ((float)(44.0/45.0)*k1 - (float)(56.0/15.0)*k2
                                    + (float)(32.0/9.0)*k3));
            float k5 = feval(z + h * ((float)(19372.0/6561.0)*k1 - (float)(25360.0/2187.0)*k2
                                    + (float)(64448.0/6561.0)*k3 - (float)(212.0/729.0)*k4));
            float k6 = feval(z + h * ((float)(9017.0/3168.0)*k1 - (float)(355.0/33.0)*k2
                                    + (float)(46732.0/5247.0)*k3 + (float)(49.0/176.0)*k4
                                    - (float)(5103.0/18656.0)*k5));
            z = z + h * ((float)(35.0/384.0)*k1 + (float)(500.0/1113.0)*k3
                       + (float)(125.0/192.0)*k4 - (float)(2187.0/6784.0)*k5
                       + (float)(11.0/84.0)*k6);
        }
        if (lane < 16) {
            ztraj[(iv + 1) * 16 + lane] = z;
            zdiff[iv * 16 + lane] = (z - zstart) / dt;
        }
    }
}

// ---------------------------------------------------------------------------
// Decoder: fused 3-layer MLP over 51200 rows. M-tile=16, 256 threads,
// thread micro-tile 2 rows x 16 cols.
// ---------------------------------------------------------------------------
#define GS 516

__global__ __launch_bounds__(256, 2) void dec_kernel(
    const float* __restrict__ ztr,
    const float* __restrict__ w1, const float* __restrict__ b1,
    const float* __restrict__ w2, const float* __restrict__ b2,
    const float* __restrict__ w3, const float* __restrict__ b3,
    float* __restrict__ xhat)
{
    __shared__ __align__(16) float zt[16 * 17];
    __shared__ __align__(16) float g[16 * GS];

    const int t    = threadIdx.x;
    const int blk  = blockIdx.x;
    const int tr   = t >> 5;
    const int tc   = t & 31;
    const int row0 = blk * 16;
    const int r0   = 2 * tr;

    {
        int r = t >> 4, d = t & 15;
        zt[r * 17 + d] = ztr[(row0 + r) * 16 + d];
    }
    __syncthreads();

    // Phase A: g1 = relu(z @ w1 + b1), K=16
    {
        float acc[2][16];
#pragma unroll
        for (int p = 0; p < 2; ++p)
#pragma unroll
            for (int i = 0; i < 16; ++i) acc[p][i] = 0.0f;

#pragma unroll
        for (int k = 0; k < 16; ++k) {
            float a0 = zt[(r0 + 0) * 17 + k];
            float a1 = zt[(r0 + 1) * 17 + k];
            const float4* wr = (const float4*)(w1 + k * 512 + 16 * tc);
#pragma unroll
            for (int u = 0; u < 4; ++u) {
                float4 wv = wr[u];
                acc[0][4*u+0] = fmaf(a0, wv.x, acc[0][4*u+0]);
                acc[0][4*u+1] = fmaf(a0, wv.y, acc[0][4*u+1]);
                acc[0][4*u+2] = fmaf(a0, wv.z, acc[0][4*u+2]);
                acc[0][4*u+3] = fmaf(a0, wv.w, acc[0][4*u+3]);
                acc[1][4*u+0] = fmaf(a1, wv.x, acc[1][4*u+0]);
                acc[1][4*u+1] = fmaf(a1, wv.y, acc[1][4*u+1]);
                acc[1][4*u+2] = fmaf(a1, wv.z, acc[1][4*u+2]);
                acc[1][4*u+3] = fmaf(a1, wv.w, acc[1][4*u+3]);
            }
        }
        const float4* bb = (const float4*)(b1 + 16 * tc);
#pragma unroll
        for (int u = 0; u < 4; ++u) {
            float4 bv = bb[u];
#pragma unroll
            for (int p = 0; p < 2; ++p) {
                g[(r0+p)*GS + 16*tc + 4*u + 0] = fmaxf(acc[p][4*u+0] + bv.x, 0.0f);
                g[(r0+p)*GS + 16*tc + 4*u + 1] = fmaxf(acc[p][4*u+1] + bv.y, 0.0f);
                g[(r0+p)*GS + 16*tc + 4*u + 2] = fmaxf(acc[p][4*u+2] + bv.z, 0.0f);
                g[(r0+p)*GS + 16*tc + 4*u + 3] = fmaxf(acc[p][4*u+3] + bv.w, 0.0f);
            }
        }
    }
    __syncthreads();

    // Phase B: g2 = relu(g1 @ w2 + b2), K=512
    {
        float accB[2][16];
#pragma unroll
        for (int p = 0; p < 2; ++p)
#pragma unroll
            for (int i = 0; i < 16; ++i) accB[p][i] = 0.0f;

        for (int k4 = 0; k4 < 128; ++k4) {
            float4 av0 = *(const float4*)&g[(r0 + 0) * GS + 4 * k4];
            float4 av1 = *(const float4*)&g[(r0 + 1) * GS + 4 * k4];
            float a0[4] = {av0.x, av0.y, av0.z, av0.w};
            float a1[4] = {av1.x, av1.y, av1.z, av1.w};
#pragma unroll
            for (int u = 0; u < 4; ++u) {
                const float4* wr = (const float4*)(w2 + (4 * k4 + u) * 512 + 16 * tc);
#pragma unroll
                for (int q = 0; q < 4; ++q) {
                    float4 wv = wr[q];
                    accB[0][4*q+0] = fmaf(a0[u], wv.x, accB[0][4*q+0]);
                    accB[0][4*q+1] = fmaf(a0[u], wv.y, accB[0][4*q+1]);
                    accB[0][4*q+2] = fmaf(a0[u], wv.z, accB[0][4*q+2]);
                    accB[0][4*q+3] = fmaf(a0[u], wv.w, accB[0][4*q+3]);
                    accB[1][4*q+0] = fmaf(a1[u], wv.x, accB[1][4*q+0]);
                    accB[1][4*q+1] = fmaf(a1[u], wv.y, accB[1][4*q+1]);
                    accB[1][4*q+2] = fmaf(a1[u], wv.z, accB[1][4*q+2]);
                    accB[1][4*q+3] = fmaf(a1[u], wv.w, accB[1][4*q+3]);
                }
            }
        }
        __syncthreads();
        const float4* bb = (const float4*)(b2 + 16 * tc);
#pragma unroll
        for (int u = 0; u < 4; ++u) {
            float4 bv = bb[u];
#pragma unroll
            for (int p = 0; p < 2; ++p) {
                g[(r0+p)*GS + 16*tc + 4*u + 0] = fmaxf(accB[p][4*u+0] + bv.x, 0.0f);
                g[(r0+p)*GS + 16*tc + 4*u + 1] = fmaxf(accB[p][4*u+1] + bv.y, 0.0f);
                g[(r0+p)*GS + 16*tc + 4*u + 2] = fmaxf(accB[p][4*u+2] + bv.z, 0.0f);
                g[(r0+p)*GS + 16*tc + 4*u + 3] = fmaxf(accB[p][4*u+3] + bv.w, 0.0f);
            }
        }
    }
    __syncthreads();

    // Phase C: xhat = g2 @ w3 + b3, N=256, K=512
    {
        float accC[2][8];
#pragma unroll
        for (int p = 0; p < 2; ++p)
#pragma unroll
            for (int i = 0; i < 8; ++i) accC[p][i] = 0.0f;

        for (int k4 = 0; k4 < 128; ++k4) {
            float4 av0 = *(const float4*)&g[(r0 + 0) * GS + 4 * k4];
            float4 av1 = *(const float4*)&g[(r0 + 1) * GS + 4 * k4];
            float a0[4] = {av0.x, av0.y, av0.z, av0.w};
            float a1[4] = {av1.x, av1.y, av1.z, av1.w};
#pragma unroll
            for (int u = 0; u < 4; ++u) {
                const float4* wr = (const float4*)(w3 + (4 * k4 + u) * 256 + 8 * tc);
                float4 w0 = wr[0], w1v = wr[1];
                accC[0][0] = fmaf(a0[u], w0.x,  accC[0][0]);
                accC[0][1] = fmaf(a0[u], w0.y,  accC[0][1]);
                accC[0][2] = fmaf(a0[u], w0.z,  accC[0][2]);
                accC[0][3] = fmaf(a0[u], w0.w,  accC[0][3]);
                accC[0][4] = fmaf(a0[u], w1v.x, accC[0][4]);
                accC[0][5] = fmaf(a0[u], w1v.y, accC[0][5]);
                accC[0][6] = fmaf(a0[u], w1v.z, accC[0][6]);
                accC[0][7] = fmaf(a0[u], w1v.w, accC[0][7]);
                accC[1][0] = fmaf(a1[u], w0.x,  accC[1][0]);
                accC[1][1] = fmaf(a1[u], w0.y,  accC[1][1]);
                accC[1][2] = fmaf(a1[u], w0.z,  accC[1][2]);
                accC[1][3] = fmaf(a1[u], w0.w,  accC[1][3]);
                accC[1][4] = fmaf(a1[u], w1v.x, accC[1][4]);
                accC[1][5] = fmaf(a1[u], w1v.y, accC[1][5]);
                accC[1][6] = fmaf(a1[u], w1v.z, accC[1][6]);
                accC[1][7] = fmaf(a1[u], w1v.w, accC[1][7]);
            }
        }
        const float4* bb = (const float4*)(b3 + 8 * tc);
        float4 bv0 = bb[0], bv1 = bb[1];
#pragma unroll
        for (int p = 0; p < 2; ++p) {
            float4 o0 = make_float4(accC[p][0] + bv0.x, accC[p][1] + bv0.y,
                                    accC[p][2] + bv0.z, accC[p][3] + bv0.w);
            float4 o1 = make_float4(accC[p][4] + bv1.x, accC[p][5] + bv1.y,
                                    accC[p][6] + bv1.z, accC[p][7] + bv1.w);
            float* dst = xhat + (size_t)(row0 + r0 + p) * 256 + 8 * tc;
            *(float4*)(dst)     = o0;
            *(float4*)(dst + 4) = o1;
        }
    }
}

extern "C" void kernel_launch(void* const* d_in, const int* in_sizes, int n_in,
                              void* d_out, int out_size, void* d_ws, size_t ws_size,
                              hipStream_t stream) {
    const float* x_seq  = (const float*)d_in[0];
    const float* tvec   = (const float*)d_in[1];
    const float* eps    = (const float*)d_in[2];
    const float* enc_w1 = (const float*)d_in[3];
    const float* enc_b1 = (const float*)d_in[4];
    const float* enc_w2 = (const float*)d_in[5];
    const float* enc_b2 = (const float*)d_in[6];
    const float* enc_w3 = (const float*)d_in[7];
    const float* enc_b3 = (const float*)d_in[8];
    const float* mu_w   = (const float*)d_in[9];
    const float* mu_b   = (const float*)d_in[10];
    const float* lv_w   = (const float*)d_in[11];
    const float* lv_b   = (const float*)d_in[12];
    const float* ode_w1 = (const float*)d_in[13];
    const float* ode_b1 = (const float*)d_in[14];
    const float* ode_w2 = (const float*)d_in[15];
    const float* ode_b2 = (const float*)d_in[16];
    const float* ode_w3 = (const float*)d_in[17];
    const float* ode_b3 = (const float*)d_in[18];
    const float* ln_g   = (const float*)d_in[19];
    const float* ln_b   = (const float*)d_in[20];
    const float* dec_w1 = (const float*)d_in[21];
    const float* dec_b1 = (const float*)d_in[22];
    const float* dec_w2 = (const float*)d_in[23];
    const float* dec_b2 = (const float*)d_in[24];
    const float* dec_w3 = (const float*)d_in[25];
    const float* dec_b3 = (const float*)d_in[26];
    float* out = (float*)d_out;

    enc_kernel<<<256, 256, 0, stream>>>(x_seq, eps, enc_w1, enc_b1, enc_w2, enc_b2,
                                        enc_w3, enc_b3, mu_w, mu_b, lv_w, lv_b, out);
    ode_kernel<<<256, 64, 0, stream>>>(tvec, ode_w1, ode_b1, ode_w2, ode_b2,
                                       ode_w3, ode_b3, ln_g, ln_b, out);
    dec_kernel<<<3200, 256, 0, stream>>>(out + OFF_ZT, dec_w1, dec_b1, dec_w2, dec_b2,
                                         dec_w3, dec_b3, out);
}

// Round 6
// 16251.067 us; speedup vs baseline: 1.6276x; 1.0194x over previous
//
#include <hip/hip_runtime.h>

// Output layout (flat f32, reference return order):
//   xhat  : B*L*N   = 13,107,200  @ 0
//   mu    : B*D     =      4,096  @ 13,107,200
//   logvar: B*D     =      4,096  @ 13,111,296
//   z_traj: B*L*D   =    819,200  @ 13,115,392
//   zdiff : B*(L-1)*D =  815,104  @ 13,934,592
#define OFF_MU   13107200
#define OFF_LV   13111296
#define OFF_ZT   13115392
#define OFF_ZD   13934592

__device__ __forceinline__ float silu_f(float x) {
    return x * __frcp_rn(1.0f + __expf(-x));
}

// DPP helpers. row_ror:N rotates within each 16-lane row; lane i receives
// the value from lane (i-N) & 15  (AMD cross-lane semantics: shr/ror read
// from LOWER lanes — verified by the canonical row_shr:1 scan idiom).
template <int CTRL>
__device__ __forceinline__ float dpp_mov(float x) {
    int y = __builtin_amdgcn_update_dpp(0, __float_as_int(x), CTRL, 0xF, 0xF, true);
    return __int_as_float(y);
}
template <int CTRL>
__device__ __forceinline__ float dpp_ror_add(float x) {
    return x + dpp_mov<CTRL>(x);
}
__device__ __forceinline__ float row_sum16(float x) {
    x = dpp_ror_add<0x128>(x);   // row_ror:8
    x = dpp_ror_add<0x124>(x);   // row_ror:4
    x = dpp_ror_add<0x122>(x);   // row_ror:2
    x = dpp_ror_add<0x121>(x);   // row_ror:1
    return x;
}

// ---------------------------------------------------------------------------
// Encoder: one block per batch row. x0(256) -> 512 -> 256 -> 128 -> mu/lv(16)
// ---------------------------------------------------------------------------
__global__ __launch_bounds__(256) void enc_kernel(
    const float* __restrict__ xseq, const float* __restrict__ eps,
    const float* __restrict__ w1, const float* __restrict__ b1,
    const float* __restrict__ w2, const float* __restrict__ b2,
    const float* __restrict__ w3, const float* __restrict__ b3,
    const float* __restrict__ muw, const float* __restrict__ mub,
    const float* __restrict__ lvw, const float* __restrict__ lvb,
    float* __restrict__ out)
{
    __shared__ float xr[256];
    __shared__ float h1[512];
    __shared__ float h2[256];
    __shared__ float h3[128];

    const int t = threadIdx.x;
    const int b = blockIdx.x;

    xr[t] = xseq[b * (200 * 256) + t];
    __syncthreads();

    {
        float acc0 = b1[t], acc1 = b1[t + 256];
        for (int i = 0; i < 256; ++i) {
            float xv = xr[i];
            acc0 = fmaf(xv, w1[i * 512 + t],       acc0);
            acc1 = fmaf(xv, w1[i * 512 + t + 256], acc1);
        }
        h1[t]       = fmaxf(acc0, 0.0f);
        h1[t + 256] = fmaxf(acc1, 0.0f);
    }
    __syncthreads();

    {
        float acc = b2[t];
        for (int i = 0; i < 512; ++i) acc = fmaf(h1[i], w2[i * 256 + t], acc);
        h2[t] = fmaxf(acc, 0.0f);
    }
    __syncthreads();

    if (t < 128) {
        float acc = b3[t];
        for (int i = 0; i < 256; ++i) acc = fmaf(h2[i], w3[i * 128 + t], acc);
        h3[t] = fmaxf(acc, 0.0f);
    }
    __syncthreads();

    if (t < 16) {
        float mu = mub[t], lv = lvb[t];
        for (int i = 0; i < 128; ++i) {
            float hv = h3[i];
            mu = fmaf(hv, muw[i * 16 + t], mu);
            lv = fmaf(hv, lvw[i * 16 + t], lv);
        }
        out[OFF_MU + b * 16 + t] = mu;
        out[OFF_LV + b * 16 + t] = lv;
        float z0 = mu + __expf(0.5f * lv) * eps[b * 16 + t];
        out[OFF_ZT + b * 3200 + t] = z0;
    }
}

// ---------------------------------------------------------------------------
// ODE integrator: ONE 64-lane WAVE per batch element (256 blocks x 64 thr).
// R6 = R5 with the DPP ring direction FIXED: after s steps of row_ror:1,
// lane d holds z[(d-s)&15], so w1 is pre-permuted with k=(d-s)&15.
// (R5 used (d+s)&15 — wrong direction — and failed correctness.)
// 2 waitcnt-only syncs per feval (a1, a2); no zarg LDS round-trip.
// w2: col j0 registers, col j1 LDS (0-conflict layout from R4).
// ---------------------------------------------------------------------------
__global__
__attribute__((amdgpu_flat_work_group_size(64, 64)))
__attribute__((amdgpu_waves_per_eu(1, 1)))
void ode_kernel(
    const float* __restrict__ tvec,
    const float* __restrict__ ow1, const float* __restrict__ ob1,
    const float* __restrict__ ow2, const float* __restrict__ ob2,
    const float* __restrict__ ow3, const float* __restrict__ ob3,
    const float* __restrict__ lng, const float* __restrict__ lnb,
    float* __restrict__ out)
{
    __shared__ __align__(16) float  a1s[128];
    __shared__ __align__(16) float  a2s[128];
    __shared__ __align__(16) float4 w2L[32 * 64];   // [p][lane]: col j1, k=4p..4p+3
    __shared__ __align__(16) float4 w3L[8 * 64];    // [t][lane]: pre-permuted

    const int lane = threadIdx.x;
    const int b    = blockIdx.x;
    const int r    = lane >> 4;
    const int d    = lane & 15;
    const int j0   = lane;
    const int j1   = lane + 64;

    // ---- w1 pre-permuted for the DPP ring: step s the lane holds z[(d-s)&15] ----
    float w1p0[16], w1p1[16];
#pragma unroll
    for (int s = 0; s < 16; ++s) {
        int k = (d - s) & 15;
        w1p0[s] = ow1[k * 128 + j0];
        w1p1[s] = ow1[k * 128 + j1];
    }
    // ---- w2 col j0 in registers (statically indexed) ----
    float4 w2q0[32];
#pragma unroll
    for (int q = 0; q < 32; ++q) {
        w2q0[q] = make_float4(ow2[(4*q+0)*128 + j0], ow2[(4*q+1)*128 + j0],
                              ow2[(4*q+2)*128 + j0], ow2[(4*q+3)*128 + j0]);
    }
    // ---- LDS-resident weights: w2 col j1, w3 (pre-permuted stagger) ----
#pragma unroll
    for (int q = 0; q < 32; ++q) {
        w2L[q * 64 + lane] = make_float4(ow2[(4*q+0)*128 + j1], ow2[(4*q+1)*128 + j1],
                                         ow2[(4*q+2)*128 + j1], ow2[(4*q+3)*128 + j1]);
    }
#pragma unroll
    for (int t = 0; t < 8; ++t) {
        int i  = (t + 2 * r) & 7;          // stagger: rows hit disjoint banks
        int k0 = 32 * r + 4 * i;
        w3L[t * 64 + lane] = make_float4(ow3[(k0+0)*16 + d], ow3[(k0+1)*16 + d],
                                         ow3[(k0+2)*16 + d], ow3[(k0+3)*16 + d]);
    }

    const float b1j0 = ob1[j0], b1j1 = ob1[j1];
    const float b2j0 = ob2[j0], b2j1 = ob2[j1];
    const float b3d  = ob3[d];
    const float lngd = lng[d];
    const float lnbd = lnb[d];

    float* ztraj = out + OFF_ZT + b * 3200;   // [200][16]
    float* zdiff = out + OFF_ZD + b * 3184;   // [199][16]

    float z = ztraj[d];   // broadcast read; replicated across the 4 rows
    __syncthreads();

    // feval: input za = per-lane z value for dim d (replicated across rows);
    // output = LN(f(z))[d], same layout. L1 is a DPP ring over the row-of-16.
    auto feval = [&](float za) -> float {
        // L1 ring: at step s the lane holds z[(d-s)&15]; weights pre-permuted.
        float acc0 = b1j0, acc1 = b1j1;
        float v = za;
#pragma unroll
        for (int s = 0; s < 16; ++s) {
            acc0 = fmaf(v, w1p0[s], acc0);
            acc1 = fmaf(v, w1p1[s], acc1);
            if (s < 15) v = dpp_mov<0x121>(v);   // row_ror:1
        }
        a1s[j0] = silu_f(acc0);
        a1s[j1] = silu_f(acc1);
        __syncthreads();   // single wave: waitcnt only

        // L2: col j0 from registers, col j1 from LDS; 2 chains per column.
        float c0a = 0.0f, c0b = 0.0f, c1a = 0.0f, c1b = 0.0f;
        const float4* A4 = (const float4*)a1s;
#pragma unroll
        for (int p = 0; p < 16; ++p) {
            float4 a  = A4[2 * p];               // broadcast
            float4 bq = A4[2 * p + 1];           // broadcast
            float4 u0 = w2q0[2 * p], u1 = w2q0[2 * p + 1];
            float4 v0 = w2L[(2 * p) * 64 + lane];
            float4 v1 = w2L[(2 * p + 1) * 64 + lane];
            c0a = fmaf(a.x,  u0.x, c0a); c1a = fmaf(a.x,  v0.x, c1a);
            c0a = fmaf(a.y,  u0.y, c0a); c1a = fmaf(a.y,  v0.y, c1a);
            c0a = fmaf(a.z,  u0.z, c0a); c1a = fmaf(a.z,  v0.z, c1a);
            c0a = fmaf(a.w,  u0.w, c0a); c1a = fmaf(a.w,  v0.w, c1a);
            c0b = fmaf(bq.x, u1.x, c0b); c1b = fmaf(bq.x, v1.x, c1b);
            c0b = fmaf(bq.y, u1.y, c0b); c1b = fmaf(bq.y, v1.y, c1b);
            c0b = fmaf(bq.z, u1.z, c0b); c1b = fmaf(bq.z, v1.z, c1b);
            c0b = fmaf(bq.w, u1.w, c0b); c1b = fmaf(bq.w, v1.w, c1b);
        }
        a2s[j0] = silu_f(c0a + c0b + b2j0);
        a2s[j1] = silu_f(c1a + c1b + b2j1);
        __syncthreads();

        // L3 partial: lane (r,d) covers k in [32r,32r+32); staggered a2 reads
        // (row-broadcast, disjoint banks across rows); w3L pre-permuted.
        float pA = 0.0f, pB = 0.0f;
        const float4* B4 = (const float4*)a2s;
#pragma unroll
        for (int t = 0; t < 8; ++t) {
            int i = (t + 2 * r) & 7;
            float4 a = B4[r * 8 + i];
            float4 w = w3L[t * 64 + lane];
            pA = fmaf(a.x, w.x, pA);
            pB = fmaf(a.y, w.y, pB);
            pA = fmaf(a.z, w.z, pA);
            pB = fmaf(a.w, w.w, pB);
        }
        // cross-row reduce (lanes d, d+16, d+32, d+48)
        float part = pA + pB;
        part += __shfl_xor(part, 16);
        part += __shfl_xor(part, 32);
        float dz = part + b3d;

        // LayerNorm over the 16 dims (intra-row DPP reduction, all lanes)
        float m  = row_sum16(dz) * 0.0625f;
        float df = dz - m;
        float vv = row_sum16(df * df) * 0.0625f;
        return df * rsqrtf(vv + 1e-5f) * lngd + lnbd;
    };

    for (int iv = 0; iv < 199; ++iv) {
        const float dt = tvec[iv + 1] - tvec[iv];
        const float h  = dt * 0.125f;
        const float zstart = z;
        for (int s = 0; s < 8; ++s) {
            float k1 = feval(z);
            float k2 = feval(z + h * (0.2f * k1));
            float k3 = feval(z + h * ((float)(3.0/40.0)*k1 + (float)(9.0/40.0)*k2));
            float k4 = feval(z + h * ((float)(44.0/45.0)*k1 - (float)(56.0/15.0)*k2
                                    + (float)(32.0/9.0)*k3));
            float k5 = feval(z + h * ((float)(19372.0/6561.0)*k1 - (float)(25360.0/2187.0)*k2
                                    + (float)(64448.0/6561.0)*k3 - (float)(212.0/729.0)*k4));
            float k6 = feval(z + h * ((float)(9017.0/3168.0)*k1 - (float)(355.0/33.0)*k2
                                    + (float)(46732.0/5247.0)*k3 + (float)(49.0/176.0)*k4
                                    - (float)(5103.0/18656.0)*k5));
            z = z + h * ((float)(35.0/384.0)*k1 + (float)(500.0/1113.0)*k3
                       + (float)(125.0/192.0)*k4 - (float)(2187.0/6784.0)*k5
                       + (float)(11.0/84.0)*k6);
        }
        if (lane < 16) {
            ztraj[(iv + 1) * 16 + lane] = z;
            zdiff[iv * 16 + lane] = (z - zstart) / dt;
        }
    }
}

// ---------------------------------------------------------------------------
// Decoder: fused 3-layer MLP over 51200 rows. M-tile=16, 256 threads,
// thread micro-tile 2 rows x 16 cols.
// ---------------------------------------------------------------------------
#define GS 516

__global__ __launch_bounds__(256, 2) void dec_kernel(
    const float* __restrict__ ztr,
    const float* __restrict__ w1, const float* __restrict__ b1,
    const float* __restrict__ w2, const float* __restrict__ b2,
    const float* __restrict__ w3, const float* __restrict__ b3,
    float* __restrict__ xhat)
{
    __shared__ __align__(16) float zt[16 * 17];
    __shared__ __align__(16) float g[16 * GS];

    const int t    = threadIdx.x;
    const int blk  = blockIdx.x;
    const int tr   = t >> 5;
    const int tc   = t & 31;
    const int row0 = blk * 16;
    const int r0   = 2 * tr;

    {
        int r = t >> 4, d = t & 15;
        zt[r * 17 + d] = ztr[(row0 + r) * 16 + d];
    }
    __syncthreads();

    // Phase A: g1 = relu(z @ w1 + b1), K=16
    {
        float acc[2][16];
#pragma unroll
        for (int p = 0; p < 2; ++p)
#pragma unroll
            for (int i = 0; i < 16; ++i) acc[p][i] = 0.0f;

#pragma unroll
        for (int k = 0; k < 16; ++k) {
            float a0 = zt[(r0 + 0) * 17 + k];
            float a1 = zt[(r0 + 1) * 17 + k];
            const float4* wr = (const float4*)(w1 + k * 512 + 16 * tc);
#pragma unroll
            for (int u = 0; u < 4; ++u) {
                float4 wv = wr[u];
                acc[0][4*u+0] = fmaf(a0, wv.x, acc[0][4*u+0]);
                acc[0][4*u+1] = fmaf(a0, wv.y, acc[0][4*u+1]);
                acc[0][4*u+2] = fmaf(a0, wv.z, acc[0][4*u+2]);
                acc[0][4*u+3] = fmaf(a0, wv.w, acc[0][4*u+3]);
                acc[1][4*u+0] = fmaf(a1, wv.x, acc[1][4*u+0]);
                acc[1][4*u+1] = fmaf(a1, wv.y, acc[1][4*u+1]);
                acc[1][4*u+2] = fmaf(a1, wv.z, acc[1][4*u+2]);
                acc[1][4*u+3] = fmaf(a1, wv.w, acc[1][4*u+3]);
            }
        }
        const float4* bb = (const float4*)(b1 + 16 * tc);
#pragma unroll
        for (int u = 0; u < 4; ++u) {
            float4 bv = bb[u];
#pragma unroll
            for (int p = 0; p < 2; ++p) {
                g[(r0+p)*GS + 16*tc + 4*u + 0] = fmaxf(acc[p][4*u+0] + bv.x, 0.0f);
                g[(r0+p)*GS + 16*tc + 4*u + 1] = fmaxf(acc[p][4*u+1] + bv.y, 0.0f);
                g[(r0+p)*GS + 16*tc + 4*u + 2] = fmaxf(acc[p][4*u+2] + bv.z, 0.0f);
                g[(r0+p)*GS + 16*tc + 4*u + 3] = fmaxf(acc[p][4*u+3] + bv.w, 0.0f);
            }
        }
    }
    __syncthreads();

    // Phase B: g2 = relu(g1 @ w2 + b2), K=512
    {
        float accB[2][16];
#pragma unroll
        for (int p = 0; p < 2; ++p)
#pragma unroll
            for (int i = 0; i < 16; ++i) accB[p][i] = 0.0f;

        for (int k4 = 0; k4 < 128; ++k4) {
            float4 av0 = *(const float4*)&g[(r0 + 0) * GS + 4 * k4];
            float4 av1 = *(const float4*)&g[(r0 + 1) * GS + 4 * k4];
            float a0[4] = {av0.x, av0.y, av0.z, av0.w};
            float a1[4] = {av1.x, av1.y, av1.z, av1.w};
#pragma unroll
            for (int u = 0; u < 4; ++u) {
                const float4* wr = (const float4*)(w2 + (4 * k4 + u) * 512 + 16 * tc);
#pragma unroll
                for (int q = 0; q < 4; ++q) {
                    float4 wv = wr[q];
                    accB[0][4*q+0] = fmaf(a0[u], wv.x, accB[0][4*q+0]);
                    accB[0][4*q+1] = fmaf(a0[u], wv.y, accB[0][4*q+1]);
                    accB[0][4*q+2] = fmaf(a0[u], wv.z, accB[0][4*q+2]);
                    accB[0][4*q+3] = fmaf(a0[u], wv.w, accB[0][4*q+3]);
                    accB[1][4*q+0] = fmaf(a1[u], wv.x, accB[1][4*q+0]);
                    accB[1][4*q+1] = fmaf(a1[u], wv.y, accB[1][4*q+1]);
                    accB[1][4*q+2] = fmaf(a1[u], wv.z, accB[1][4*q+2]);
                    accB[1][4*q+3] = fmaf(a1[u], wv.w, accB[1][4*q+3]);
                }
            }
        }
        __syncthreads();
        const float4* bb = (const float4*)(b2 + 16 * tc);
#pragma unroll
        for (int u = 0; u < 4; ++u) {
            float4 bv = bb[u];
#pragma unroll
            for (int p = 0; p < 2; ++p) {
                g[(r0+p)*GS + 16*tc + 4*u + 0] = fmaxf(accB[p][4*u+0] + bv.x, 0.0f);
                g[(r0+p)*GS + 16*tc + 4*u + 1] = fmaxf(accB[p][4*u+1] + bv.y, 0.0f);
                g[(r0+p)*GS + 16*tc + 4*u + 2] = fmaxf(accB[p][4*u+2] + bv.z, 0.0f);
                g[(r0+p)*GS + 16*tc + 4*u + 3] = fmaxf(accB[p][4*u+3] + bv.w, 0.0f);
            }
        }
    }
    __syncthreads();

    // Phase C: xhat = g2 @ w3 + b3, N=256, K=512
    {
        float accC[2][8];
#pragma unroll
        for (int p = 0; p < 2; ++p)
#pragma unroll
            for (int i = 0; i < 8; ++i) accC[p][i] = 0.0f;

        for (int k4 = 0; k4 < 128; ++k4) {
            float4 av0 = *(const float4*)&g[(r0 + 0) * GS + 4 * k4];
            float4 av1 = *(const float4*)&g[(r0 + 1) * GS + 4 * k4];
            float a0[4] = {av0.x, av0.y, av0.z, av0.w};
            float a1[4] = {av1.x, av1.y, av1.z, av1.w};
#pragma unroll
            for (int u = 0; u < 4; ++u) {
                const float4* wr = (const float4*)(w3 + (4 * k4 + u) * 256 + 8 * tc);
                float4 w0 = wr[0], w1v = wr[1];
                accC[0][0] = fmaf(a0[u], w0.x,  accC[0][0]);
                accC[0][1] = fmaf(a0[u], w0.y,  accC[0][1]);
                accC[0][2] = fmaf(a0[u], w0.z,  accC[0][2]);
                accC[0][3] = fmaf(a0[u], w0.w,  accC[0][3]);
                accC[0][4] = fmaf(a0[u], w1v.x, accC[0][4]);
                accC[0][5] = fmaf(a0[u], w1v.y, accC[0][5]);
                accC[0][6] = fmaf(a0[u], w1v.z, accC[0][6]);
                accC[0][7] = fmaf(a0[u], w1v.w, accC[0][7]);
                accC[1][0] = fmaf(a1[u], w0.x,  accC[1][0]);
                accC[1][1] = fmaf(a1[u], w0.y,  accC[1][1]);
                accC[1][2] = fmaf(a1[u], w0.z,  accC[1][2]);
                accC[1][3] = fmaf(a1[u], w0.w,  accC[1][3]);
                accC[1][4] = fmaf(a1[u], w1v.x, accC[1][4]);
                accC[1][5] = fmaf(a1[u], w1v.y, accC[1][5]);
                accC[1][6] = fmaf(a1[u], w1v.z, accC[1][6]);
                accC[1][7] = fmaf(a1[u], w1v.w, accC[1][7]);
            }
        }
        const float4* bb = (const float4*)(b3 + 8 * tc);
        float4 bv0 = bb[0], bv1 = bb[1];
#pragma unroll
        for (int p = 0; p < 2; ++p) {
            float4 o0 = make_float4(accC[p][0] + bv0.x, accC[p][1] + bv0.y,
                                    accC[p][2] + bv0.z, accC[p][3] + bv0.w);
            float4 o1 = make_float4(accC[p][4] + bv1.x, accC[p][5] + bv1.y,
                                    accC[p][6] + bv1.z, accC[p][7] + bv1.w);
            float* dst = xhat + (size_t)(row0 + r0 + p) * 256 + 8 * tc;
            *(float4*)(dst)     = o0;
            *(float4*)(dst + 4) = o1;
        }
    }
}

extern "C" void kernel_launch(void* const* d_in, const int* in_sizes, int n_in,
                              void* d_out, int out_size, void* d_ws, size_t ws_size,
                              hipStream_t stream) {
    const float* x_seq  = (const float*)d_in[0];
    const float* tvec   = (const float*)d_in[1];
    const float* eps    = (const float*)d_in[2];
    const float* enc_w1 = (const float*)d_in[3];
    const float* enc_b1 = (const float*)d_in[4];
    const float* enc_w2 = (const float*)d_in[5];
    const float* enc_b2 = (const float*)d_in[6];
    const float* enc_w3 = (const float*)d_in[7];
    const float* enc_b3 = (const float*)d_in[8];
    const float* mu_w   = (const float*)d_in[9];
    const float* mu_b   = (const float*)d_in[10];
    const float* lv_w   = (const float*)d_in[11];
    const float* lv_b   = (const float*)d_in[12];
    const float* ode_w1 = (const float*)d_in[13];
    const float* ode_b1 = (const float*)d_in[14];
    const float* ode_w2 = (const float*)d_in[15];
    const float* ode_b2 = (const float*)d_in[16];
    const float* ode_w3 = (const float*)d_in[17];
    const float* ode_b3 = (const float*)d_in[18];
    const float* ln_g   = (const float*)d_in[19];
    const float* ln_b   = (const float*)d_in[20];
    const float* dec_w1 = (const float*)d_in[21];
    const float* dec_b1 = (const float*)d_in[22];
    const float* dec_w2 = (const float*)d_in[23];
    const float* dec_b2 = (const float*)d_in[24];
    const float* dec_w3 = (const float*)d_in[25];
    const float* dec_b3 = (const float*)d_in[26];
    float* out = (float*)d_out;

    enc_kernel<<<256, 256, 0, stream>>>(x_seq, eps, enc_w1, enc_b1, enc_w2, enc_b2,
                                        enc_w3, enc_b3, mu_w, mu_b, lv_w, lv_b, out);
    ode_kernel<<<256, 64, 0, stream>>>(tvec, ode_w1, ode_b1, ode_w2, ode_b2,
                                       ode_w3, ode_b3, ln_g, ln_b, out);
    dec_kernel<<<3200, 256, 0, stream>>>(out + OFF_ZT, dec_w1, dec_b1, dec_w2, dec_b2,
                                         dec_w3, dec_b3, out);
}